// Round 5
// baseline (840.745 us; speedup 1.0000x reference)
//
#include <hip/hip_runtime.h>
#include <math.h>
#include <stdint.h>

#define Bz 32
#define Sz 2048
#define Dz 1024
#define Uz 1024
#define Mz (Bz*Sz)

typedef __attribute__((ext_vector_type(8))) short bf16x8;
typedef __attribute__((ext_vector_type(4))) float f32x4;

__device__ __forceinline__ unsigned short f2bf(float f) {
    union { float f; uint32_t u; } v; v.f = f;
    uint32_t r = v.u + 0x7FFFu + ((v.u >> 16) & 1u);   // RNE
    return (unsigned short)(r >> 16);
}

__device__ __forceinline__ float fast_tanh(float x) {
    float e = __expf(2.f * x);
    return 1.f - 2.f * __builtin_amdgcn_rcpf(e + 1.f);
}

#define GLD16(gsrc, ldst) \
    __builtin_amdgcn_global_load_lds((__attribute__((address_space(1))) void*)(void*)(gsrc), \
        (__attribute__((address_space(3))) void*)(ldst), 16, 0, 0)

#define CONV_BLOCKS 16384   // (Mz*Dz)/(256*16)
#define WT_BLOCKS   256
#define DEC_BLOCKS  128     // full dec projection: 32 b x 4 u-quarters
#define SINIT_BLOCKS 64     // Bz*Sz / (256*4)

// ---------------------------------------------------------------------------
// PREP (fused): h_enc->bf16 | W_enc->wT bf16 | dec_p = h_dec@W_dec + b_dec |
//               score = b_com.  The latency-bound dec blocks overlap the
//               BW-bound conv blocks inside one dispatch.
// ---------------------------------------------------------------------------
__global__ __launch_bounds__(256) void prep_kernel(
    const float* __restrict__ h_enc, unsigned short* __restrict__ hbf,
    const float* __restrict__ W_enc, unsigned short* __restrict__ wT,
    const float* __restrict__ h_dec, const float* __restrict__ W_dec,
    const float* __restrict__ b_dec, float* __restrict__ dec_p,
    const float* __restrict__ b_com, float* __restrict__ score)
{
    __shared__ float tile[64][65];
    __shared__ float hs[Dz];
    const int bid = blockIdx.x;
    const int tid = threadIdx.x;
    if (bid < CONV_BLOCKS) {
        const size_t i = ((size_t)bid * 256 + tid) * 16;
#pragma unroll
        for (int h = 0; h < 2; ++h) {
            const float4 a = *(const float4*)(h_enc + i + h * 8);
            const float4 c = *(const float4*)(h_enc + i + h * 8 + 4);
            union { unsigned short s[8]; uint4 v; } o;
            o.s[0] = f2bf(a.x); o.s[1] = f2bf(a.y); o.s[2] = f2bf(a.z); o.s[3] = f2bf(a.w);
            o.s[4] = f2bf(c.x); o.s[5] = f2bf(c.y); o.s[6] = f2bf(c.z); o.s[7] = f2bf(c.w);
            *(uint4*)(hbf + i + h * 8) = o.v;
        }
    } else if (bid < CONV_BLOCKS + WT_BLOCKS) {
        const int b2 = bid - CONV_BLOCKS;
        const int c  = tid & 63;
        const int r0 = tid >> 6;
        const int u0 = (b2 & 15) * 64;
        const int d0 = (b2 >> 4) * 64;
        for (int r = r0; r < 64; r += 4)
            tile[r][c] = W_enc[(size_t)(d0 + r) * Uz + u0 + c];
        __syncthreads();
        for (int r = r0; r < 64; r += 4)
            wT[(size_t)(u0 + r) * Dz + d0 + c] = f2bf(tile[c][r]);
    } else if (bid < CONV_BLOCKS + WT_BLOCKS + DEC_BLOCKS) {
        const int b3 = bid - (CONV_BLOCKS + WT_BLOCKS);
        const int b  = b3 >> 2;
        const int u  = ((b3 & 3) << 8) + tid;
        for (int d = tid; d < Dz; d += 256) hs[d] = h_dec[b * Dz + d];
        __syncthreads();
        float acc = 0.f;
#pragma unroll 4
        for (int d = 0; d < Dz; ++d) acc += hs[d] * W_dec[(size_t)d * Uz + u];
        dec_p[b * Uz + u] = acc + b_dec[u];
    } else {
        const int b4 = bid - (CONV_BLOCKS + WT_BLOCKS + DEC_BLOCKS);
        const float bc = b_com[0];
        const int i4 = (b4 * 256 + tid) * 4;
        float4 v = {bc, bc, bc, bc};
        *(float4*)&score[i4] = v;
    }
}

// ---------------------------------------------------------------------------
// K2 (hot, MFMA): 128x128 tile, BK=64, U split across 2 blocks (grid 1024).
// __launch_bounds__(256,3) forces <=170 unified regs -> 3 blocks/CU.
// LDS unit layout: operand X, unit (g,kg) at X + (g*2+kg)*512 shorts,
// fragment-linear [lane][8 bf16] so GLD16's base+lane*16 IS the fragment.
// Wave w stages A units g in {2w,2w+1} and B units g in {2w,2w+1}, kg in {0,1}.
// Deferred register epilogue: tanh+W_com per chunk, one shfl-reduce +
// atomicAdd at the end (score pre-initialized to b_com by prep).
// ---------------------------------------------------------------------------
__global__ __launch_bounds__(256, 3) void score_mfma_kernel(
    const unsigned short* __restrict__ hbf,   // [Mz][Dz] bf16
    const unsigned short* __restrict__ wT,    // [Uz][Dz] bf16
    const float* __restrict__ dec_p,
    const float* __restrict__ W_com,
    float* __restrict__ score)
{
    __shared__ unsigned short As[16 * 512];   // 16 KB: (mg<8, kg<2)
    __shared__ unsigned short Bs[16 * 512];   // 16 KB: (ng<8, kg<2)

    const int tid  = threadIdx.x;
    const int w    = tid >> 6;
    const int lane = tid & 63;
    const int ln   = lane & 15;
    const int q    = lane >> 4;
    const int wm   = w & 1;
    const int wn   = w >> 1;
    const int m0   = (blockIdx.x >> 1) * 128;  // 512 m-blocks
    const int ub   = (blockIdx.x & 1) * 512;   // u-half
    const int b    = m0 / Sz;

    // staging sources: wave w owns m-groups / n-groups {2w, 2w+1}
    const unsigned short* a_srcA = hbf + (size_t)(m0 + (2 * w + 0) * 16 + ln) * Dz + q * 8;
    const unsigned short* a_srcB = a_srcA + (size_t)16 * Dz;
    unsigned short* a_dst0 = As + ((2 * w + 0) * 2 + 0) * 512;  // (mg=2w,   kg=0)
    unsigned short* a_dst1 = As + ((2 * w + 0) * 2 + 1) * 512;  // (mg=2w,   kg=1)
    unsigned short* a_dst2 = As + ((2 * w + 1) * 2 + 0) * 512;  // (mg=2w+1, kg=0)
    unsigned short* a_dst3 = As + ((2 * w + 1) * 2 + 1) * 512;  // (mg=2w+1, kg=1)

    float racc[4][4];
#pragma unroll
    for (int i = 0; i < 4; ++i)
#pragma unroll
        for (int r = 0; r < 4; ++r) racc[i][r] = 0.f;

    for (int u0 = 0; u0 < 512; u0 += 128) {
        f32x4 acc[4][4];
#pragma unroll
        for (int i = 0; i < 4; ++i)
#pragma unroll
            for (int j = 0; j < 4; ++j) acc[i][j] = (f32x4){0.f, 0.f, 0.f, 0.f};

        const unsigned short* b_srcA = wT + (size_t)(ub + u0 + (2 * w + 0) * 16 + ln) * Dz + q * 8;
        const unsigned short* b_srcB = b_srcA + (size_t)16 * Dz;
        unsigned short* b_dst0 = Bs + ((2 * w + 0) * 2 + 0) * 512;
        unsigned short* b_dst1 = Bs + ((2 * w + 0) * 2 + 1) * 512;
        unsigned short* b_dst2 = Bs + ((2 * w + 1) * 2 + 0) * 512;
        unsigned short* b_dst3 = Bs + ((2 * w + 1) * 2 + 1) * 512;

        for (int k0 = 0; k0 < Dz; k0 += 64) {
            __syncthreads();                  // protect LDS from prev readers
            GLD16(a_srcA + k0,      a_dst0);
            GLD16(a_srcA + k0 + 32, a_dst1);
            GLD16(a_srcB + k0,      a_dst2);
            GLD16(a_srcB + k0 + 32, a_dst3);
            GLD16(b_srcA + k0,      b_dst0);
            GLD16(b_srcA + k0 + 32, b_dst1);
            GLD16(b_srcB + k0,      b_dst2);
            GLD16(b_srcB + k0 + 32, b_dst3);
            __syncthreads();                  // vmcnt drained before barrier

#pragma unroll
            for (int kg = 0; kg < 2; ++kg) {
                bf16x8 af[4], bfr[4];
#pragma unroll
                for (int i = 0; i < 4; ++i)
                    af[i] = *(const bf16x8*)(As + ((wm * 4 + i) * 2 + kg) * 512 + lane * 8);
#pragma unroll
                for (int j = 0; j < 4; ++j)
                    bfr[j] = *(const bf16x8*)(Bs + ((wn * 4 + j) * 2 + kg) * 512 + lane * 8);
#pragma unroll
                for (int i = 0; i < 4; ++i)
#pragma unroll
                    for (int j = 0; j < 4; ++j)
                        acc[i][j] = __builtin_amdgcn_mfma_f32_16x16x32_bf16(
                            af[i], bfr[j], acc[i][j], 0, 0, 0);
            }
        }

        // per-chunk: tanh + dot(W_com) into registers — no barrier, no LDS
        float dpv[4], wcv[4];
#pragma unroll
        for (int j = 0; j < 4; ++j) {
            const int u = ub + u0 + (wn * 4 + j) * 16 + ln;
            dpv[j] = dec_p[b * Uz + u];
            wcv[j] = W_com[u];
        }
#pragma unroll
        for (int i = 0; i < 4; ++i)
#pragma unroll
            for (int r = 0; r < 4; ++r) {
                float v = 0.f;
#pragma unroll
                for (int j = 0; j < 4; ++j)
                    v += fast_tanh(acc[i][j][r] + dpv[j]) * wcv[j];
                racc[i][r] += v;
            }
    }

    // single reduction: sum over the 16 ln-lanes, then atomicAdd partials
#pragma unroll
    for (int off = 1; off < 16; off <<= 1)
#pragma unroll
        for (int i = 0; i < 4; ++i)
#pragma unroll
            for (int r = 0; r < 4; ++r)
                racc[i][r] += __shfl_xor(racc[i][r], off, 64);
    if (ln == 0) {
#pragma unroll
        for (int i = 0; i < 4; ++i)
#pragma unroll
            for (int r = 0; r < 4; ++r)
                atomicAdd(&score[m0 + wm * 64 + i * 16 + q * 4 + r], racc[i][r]);
    }
}

// ---------------------------------------------------------------------------
// softmax (blocks 0..31) + out_ctx init = b_enc (32..63) + wsum zero (64..95)
// ---------------------------------------------------------------------------
__global__ __launch_bounds__(256) void softmax_init_kernel(
    const float* __restrict__ score, float* __restrict__ attn,
    const float* __restrict__ b_enc, float* __restrict__ out_ctx,
    float* __restrict__ wsum)
{
    __shared__ float red[256];
    const int tid = threadIdx.x;
    if (blockIdx.x >= 2 * Bz) {
        const int b3 = blockIdx.x - 2 * Bz;
        float4 z = {0.f, 0.f, 0.f, 0.f};
        *(float4*)&wsum[b3 * Dz + tid * 4] = z;
        return;
    }
    if (blockIdx.x >= Bz) {
        const int b2 = blockIdx.x - Bz;
        const int u4 = tid * 4;
        *(float4*)&out_ctx[b2 * Uz + u4] = *(const float4*)&b_enc[u4];
        return;
    }
    const int b = blockIdx.x;
    const float* srow = score + b * Sz;
    float v[8];
    float lm = -1e30f;
#pragma unroll
    for (int i = 0; i < 8; ++i) { v[i] = srow[i * 256 + tid]; lm = fmaxf(lm, v[i]); }
    red[tid] = lm; __syncthreads();
    for (int off = 128; off > 0; off >>= 1) {
        if (tid < off) red[tid] = fmaxf(red[tid], red[tid + off]);
        __syncthreads();
    }
    const float mx = red[0];
    __syncthreads();
    float ls = 0.f;
#pragma unroll
    for (int i = 0; i < 8; ++i) { v[i] = expf(v[i] - mx); ls += v[i]; }
    red[tid] = ls; __syncthreads();
    for (int off = 128; off > 0; off >>= 1) {
        if (tid < off) red[tid] += red[tid + off];
        __syncthreads();
    }
    const float inv = 1.f / red[0];
#pragma unroll
    for (int i = 0; i < 8; ++i) attn[b * Sz + i * 256 + tid] = v[i] * inv;
}

// ---------------------------------------------------------------------------
// wsum[b,d] = sum_s attn[b,s]*h_enc[b,s,d]; grid 1024 (64 s-rows per block)
// ---------------------------------------------------------------------------
__global__ __launch_bounds__(256) void wsum_kernel(
    const float* __restrict__ h_enc, const float* __restrict__ attn,
    float* __restrict__ wsum)
{
    __shared__ float aw[64];
    const int b  = blockIdx.x >> 5;
    const int s0 = (blockIdx.x & 31) * 64;
    const int tid = threadIdx.x;
    if (tid < 64) aw[tid] = attn[b * Sz + s0 + tid];
    __syncthreads();
    float4 acc = {0.f, 0.f, 0.f, 0.f};
    const float* base = h_enc + ((size_t)b * Sz + s0) * Dz + tid * 4;
#pragma unroll 4
    for (int s = 0; s < 64; ++s) {
        const float a = aw[s];
        const float4 h = *(const float4*)(base + (size_t)s * Dz);
        acc.x += a * h.x; acc.y += a * h.y; acc.z += a * h.z; acc.w += a * h.w;
    }
    float* o = wsum + b * Dz + tid * 4;
    atomicAdd(o + 0, acc.x); atomicAdd(o + 1, acc.y);
    atomicAdd(o + 2, acc.z); atomicAdd(o + 3, acc.w);
}

// ---------------------------------------------------------------------------
// out_ctx[b,u] += partial wsum[b,:]@W_enc (8 d-chunks, atop b_enc init)
// ---------------------------------------------------------------------------
__global__ __launch_bounds__(256) void ctx_partial_kernel(
    const float* __restrict__ wsum, const float* __restrict__ W_enc,
    float* __restrict__ out_ctx)
{
    __shared__ float hs[128];
    const int b  = blockIdx.x >> 3;
    const int d0 = (blockIdx.x & 7) * 128;
    const int tid = threadIdx.x;
    const int u4 = tid * 4;
    if (tid < 128) hs[tid] = wsum[b * Dz + d0 + tid];
    __syncthreads();
    float4 acc = {0.f, 0.f, 0.f, 0.f};
#pragma unroll 4
    for (int d = 0; d < 128; ++d) {
        const float  a = hs[d];
        const float4 wv = *(const float4*)&W_enc[(size_t)(d0 + d) * Uz + u4];
        acc.x += a * wv.x; acc.y += a * wv.y; acc.z += a * wv.z; acc.w += a * wv.w;
    }
    float* o = out_ctx + b * Uz + u4;
    atomicAdd(o + 0, acc.x); atomicAdd(o + 1, acc.y);
    atomicAdd(o + 2, acc.z); atomicAdd(o + 3, acc.w);
}

// ---------------------------------------------------------------------------
// Fallback fp32 path (only if ws too small for bf16 staging)
// ---------------------------------------------------------------------------
__global__ __launch_bounds__(256) void dec_proj_kernel(
    const float* __restrict__ h_dec, const float* __restrict__ W_dec,
    const float* __restrict__ b_dec, float* __restrict__ dec_p)
{
    __shared__ float hs[Dz];
    const int b = blockIdx.x >> 2;
    const int u = ((blockIdx.x & 3) << 8) + threadIdx.x;
    for (int d = threadIdx.x; d < Dz; d += 256) hs[d] = h_dec[b * Dz + d];
    __syncthreads();
    float acc = 0.f;
#pragma unroll 4
    for (int d = 0; d < Dz; ++d) acc += hs[d] * W_dec[d * Uz + u];
    dec_p[b * Uz + u] = acc + b_dec[u];
}

#define MT 64
#define NT 64
#define KT 64
__global__ __launch_bounds__(256) void score_kernel(
    const float* __restrict__ h_enc, const float* __restrict__ W_enc,
    const float* __restrict__ dec_p, const float* __restrict__ W_com,
    const float* __restrict__ b_com, float* __restrict__ score)
{
    __shared__ __align__(16) float As[KT][MT + 4];
    __shared__ __align__(16) float Bs[KT][NT + 4];
    __shared__ float red[MT][17];
    const int tid = threadIdx.x;
    const int tx = tid & 15;
    const int ty = tid >> 4;
    const int m0 = blockIdx.x * MT;
    const int b  = m0 / Sz;
    float s_acc = 0.f;
    for (int u0 = 0; u0 < Uz; u0 += NT) {
        float acc[4][4];
#pragma unroll
        for (int i = 0; i < 4; ++i)
#pragma unroll
            for (int j = 0; j < 4; ++j) acc[i][j] = 0.f;
        for (int k0 = 0; k0 < Dz; k0 += KT) {
            __syncthreads();
#pragma unroll
            for (int i = 0; i < 4; ++i) {
                const int row = ty + i * 16;
                const int c4  = tx * 4;
                const float4 v = *(const float4*)&h_enc[(size_t)(m0 + row) * Dz + k0 + c4];
                As[c4 + 0][row] = v.x; As[c4 + 1][row] = v.y;
                As[c4 + 2][row] = v.z; As[c4 + 3][row] = v.w;
            }
#pragma unroll
            for (int i = 0; i < 4; ++i) {
                const int row = ty + i * 16;
                *(float4*)&Bs[row][tx * 4] =
                    *(const float4*)&W_enc[(size_t)(k0 + row) * Uz + u0 + tx * 4];
            }
            __syncthreads();
#pragma unroll 8
            for (int k = 0; k < KT; ++k) {
                const float4 a = *(const float4*)&As[k][ty * 4];
                const float4 wv = *(const float4*)&Bs[k][tx * 4];
                acc[0][0] += a.x * wv.x; acc[0][1] += a.x * wv.y; acc[0][2] += a.x * wv.z; acc[0][3] += a.x * wv.w;
                acc[1][0] += a.y * wv.x; acc[1][1] += a.y * wv.y; acc[1][2] += a.y * wv.z; acc[1][3] += a.y * wv.w;
                acc[2][0] += a.z * wv.x; acc[2][1] += a.z * wv.y; acc[2][2] += a.z * wv.z; acc[2][3] += a.z * wv.w;
                acc[3][0] += a.w * wv.x; acc[3][1] += a.w * wv.y; acc[3][2] += a.w * wv.z; acc[3][3] += a.w * wv.w;
            }
        }
        const float4 dp = *(const float4*)&dec_p[b * Uz + u0 + tx * 4];
        const float4 wc = *(const float4*)&W_com[u0 + tx * 4];
#pragma unroll
        for (int i = 0; i < 4; ++i) {
            const float p = tanhf(acc[i][0] + dp.x) * wc.x + tanhf(acc[i][1] + dp.y) * wc.y
                          + tanhf(acc[i][2] + dp.z) * wc.z + tanhf(acc[i][3] + dp.w) * wc.w;
            red[ty * 4 + i][tx] = p;
        }
        __syncthreads();
        if (tid < MT) {
            float t = 0.f;
#pragma unroll
            for (int j = 0; j < 16; ++j) t += red[tid][j];
            s_acc += t;
        }
    }
    if (tid < MT) score[m0 + tid] = s_acc + b_com[0];
}

__global__ __launch_bounds__(256) void ctx_kernel(
    const float* __restrict__ wsum, const float* __restrict__ W_enc,
    const float* __restrict__ b_enc, float* __restrict__ out)
{
    __shared__ float hs[Dz];
    const int b = blockIdx.x >> 2;
    const int u = ((blockIdx.x & 3) << 8) + threadIdx.x;
    for (int d = threadIdx.x; d < Dz; d += 256) hs[d] = wsum[b * Dz + d];
    __syncthreads();
    float acc = 0.f;
#pragma unroll 4
    for (int d = 0; d < Dz; ++d) acc += hs[d] * W_enc[d * Uz + u];
    out[b * Uz + u] = acc + b_enc[u];
}

// ---------------------------------------------------------------------------
extern "C" void kernel_launch(void* const* d_in, const int* in_sizes, int n_in,
                              void* d_out, int out_size, void* d_ws, size_t ws_size,
                              hipStream_t stream)
{
    const float* h_enc = (const float*)d_in[0];
    const float* h_dec = (const float*)d_in[1];
    const float* W_enc = (const float*)d_in[2];
    const float* b_enc = (const float*)d_in[3];
    const float* W_dec = (const float*)d_in[4];
    const float* b_dec = (const float*)d_in[5];
    const float* W_com = (const float*)d_in[6];
    const float* b_com = (const float*)d_in[7];

    float* out_ctx  = (float*)d_out;            // [B,U]
    float* out_attn = out_ctx + Bz * Uz;        // [B,S]

    const size_t HBF_BYTES = (size_t)Mz * Dz * 2;       // 128 MiB
    const size_t WT_BYTES  = (size_t)Uz * Dz * 2;       // 2 MiB
    const size_t SMALL     = (size_t)(Bz*Uz + Bz*Sz + Bz*Dz) * 4;
    const size_t need      = HBF_BYTES + WT_BYTES + SMALL;

    if (ws_size >= need) {
        char* wsb = (char*)d_ws;
        unsigned short* hbf = (unsigned short*)wsb;
        unsigned short* wT  = (unsigned short*)(wsb + HBF_BYTES);
        float* dec_p = (float*)(wsb + HBF_BYTES + WT_BYTES);
        float* score = dec_p + Bz * Uz;
        float* wsum  = score + Bz * Sz;

        prep_kernel<<<CONV_BLOCKS + WT_BLOCKS + DEC_BLOCKS + SINIT_BLOCKS, 256, 0, stream>>>(
            h_enc, hbf, W_enc, wT, h_dec, W_dec, b_dec, dec_p, b_com, score);
        score_mfma_kernel<<<(Mz / 128) * 2, 256, 0, stream>>>(hbf, wT, dec_p, W_com, score);
        softmax_init_kernel<<<3 * Bz, 256, 0, stream>>>(score, out_attn, b_enc, out_ctx, wsum);
        wsum_kernel<<<Bz * 32, 256, 0, stream>>>(h_enc, out_attn, wsum);
        ctx_partial_kernel<<<Bz * 8, 256, 0, stream>>>(wsum, W_enc, out_ctx);
    } else {
        float* ws    = (float*)d_ws;
        float* dec_p = ws;
        float* score = ws + Bz * Uz;
        float* wsum  = ws + Bz * Uz + Bz * Sz;

        dec_proj_kernel<<<(Bz * Uz) / 256, 256, 0, stream>>>(h_dec, W_dec, b_dec, dec_p);
        score_kernel<<<Mz / MT, 256, 0, stream>>>(h_enc, W_enc, dec_p, W_com, b_com, score);
        softmax_init_kernel<<<3 * Bz, 256, 0, stream>>>(score, out_attn, b_enc, out_ctx, wsum);
        wsum_kernel<<<Bz * 32, 256, 0, stream>>>(h_enc, out_attn, wsum);
        ctx_kernel<<<(Bz * Uz) / 256, 256, 0, stream>>>(wsum, W_enc, b_enc, out_ctx);
    }
}